// Round 1
// baseline (389.226 us; speedup 1.0000x reference)
//
#include <hip/hip_runtime.h>

// ---------------------------------------------------------------------------
// CrossAttention: B=32, C=256, H=W=32 (HW=1024), Cq=128
// out[b,c,i] = sum_j v[b,c,j] * softmax_j(q^T k)[i,j] + x1[b,c,i]
//   q = Wq @ x1 + bq            [b,128,1024]
//   k = Wk[:, :256] @ x2 + kadd (pyramid channels fold into per-region bias)
//   v = Wv @ x2 + bv            [b,256,1024]
// Strategy: bf16 MFMA (16x16x32) everywhere, f32 accum; flash attention.
// ---------------------------------------------------------------------------

typedef __attribute__((ext_vector_type(8))) short short8;    // 8 bf16 (4 VGPR)
typedef __attribute__((ext_vector_type(4))) float f32x4;     // 4 f32 acc

#define MFMA(a, b, c) __builtin_amdgcn_mfma_f32_16x16x32_bf16((a), (b), (c), 0, 0, 0)

__device__ __forceinline__ unsigned short f2bf(float f) {
    unsigned u = __builtin_bit_cast(unsigned, f);
    u = (u + 0x7FFFu + ((u >> 16) & 1u)) >> 16;   // round-to-nearest-even
    return (unsigned short)u;
}

__device__ __forceinline__ short8 ld8(const unsigned short* p) {
    return *reinterpret_cast<const short8*>(p);
}

// --------------------------- f32 -> bf16 convert ---------------------------
__global__ __launch_bounds__(256) void f2bf_kernel(const float* in, unsigned short* out, int n) {
    int i = blockIdx.x * 256 + threadIdx.x;
    if (i < n) out[i] = f2bf(in[i]);
}

// ------------------- transpose [b][c=256][n=1024] f32 -> [b][n][c] bf16 ----
__global__ __launch_bounds__(256) void transpose_kernel(const float* __restrict__ x,
                                                        unsigned short* __restrict__ xt) {
    __shared__ unsigned short tile[64][65];
    int b = blockIdx.z, c0 = blockIdx.y * 64, n0 = blockIdx.x * 64;
    const float* src = x + ((size_t)b * 256 + c0) * 1024 + n0;
    int tid = threadIdx.x;
#pragma unroll
    for (int it = 0; it < 16; ++it) {
        int idx = it * 256 + tid;
        int cl = idx >> 6, nl = idx & 63;
        tile[cl][nl] = f2bf(src[(size_t)cl * 1024 + nl]);
    }
    __syncthreads();
    int nl = tid >> 2, cs = (tid & 3) * 16;
    unsigned short buf[16];
#pragma unroll
    for (int j = 0; j < 16; ++j) buf[j] = tile[cs + j][nl];
    unsigned int w[8];
#pragma unroll
    for (int k = 0; k < 8; ++k) w[k] = (unsigned)buf[2 * k] | ((unsigned)buf[2 * k + 1] << 16);
    unsigned short* dst = xt + ((size_t)b * 1024 + n0 + nl) * 256 + c0 + cs;
    uint4 u0; u0.x = w[0]; u0.y = w[1]; u0.z = w[2]; u0.w = w[3];
    uint4 u1; u1.x = w[4]; u1.y = w[5]; u1.z = w[6]; u1.w = w[7];
    reinterpret_cast<uint4*>(dst)[0] = u0;
    reinterpret_cast<uint4*>(dst)[1] = u1;
}

// ------------------------- pyramid pools of x2 -----------------------------
// one block (64 thr) per (b,c): p4[16] = 8x8 block means, p2[4], p1[1]
__global__ __launch_bounds__(64) void pool_kernel(const float* __restrict__ x2,
                                                  float* __restrict__ p1,
                                                  float* __restrict__ p2,
                                                  float* __restrict__ p4) {
    int bc = blockIdx.x;
    int t = threadIdx.x;
    const float* src = x2 + (size_t)bc * 1024;
    int dh = t >> 3, dw = t & 7;
    float s[16];
#pragma unroll
    for (int r = 0; r < 16; ++r)
        s[r] = src[((r >> 2) * 8 + dh) * 32 + (r & 3) * 8 + dw];
#pragma unroll
    for (int r = 0; r < 16; ++r) {
        float v = s[r];
        v += __shfl_xor(v, 1);  v += __shfl_xor(v, 2);  v += __shfl_xor(v, 4);
        v += __shfl_xor(v, 8);  v += __shfl_xor(v, 16); v += __shfl_xor(v, 32);
        s[r] = v;
    }
    if (t == 0) {
        float sq[4];
#pragma unroll
        for (int j = 0; j < 4; ++j) {
            int jh = j >> 1, jw = j & 1;
            sq[j] = s[8 * jh + 2 * jw] + s[8 * jh + 2 * jw + 1] +
                    s[8 * jh + 4 + 2 * jw] + s[8 * jh + 4 + 2 * jw + 1];
            p2[(size_t)bc * 4 + j] = sq[j] * (1.f / 256.f);
        }
#pragma unroll
        for (int r = 0; r < 16; ++r) p4[(size_t)bc * 16 + r] = s[r] * (1.f / 64.f);
        p1[bc] = (sq[0] + sq[1] + sq[2] + sq[3]) * (1.f / 1024.f);
    }
}

// -------- kadd[b][o][r16] = bk[o] + Wk[:,256:]·(pooled channels for r) -----
__global__ __launch_bounds__(256) void kadd_kernel(const float* __restrict__ Wk,
                                                   const float* __restrict__ bk,
                                                   const float* __restrict__ p1,
                                                   const float* __restrict__ p2,
                                                   const float* __restrict__ p4,
                                                   float* __restrict__ kadd) {
    int b = blockIdx.x >> 7, o = blockIdx.x & 127;
    int tid = threadIdx.x;
    const float* wr = Wk + (size_t)o * 1024;
    int c = tid;
    size_t bc = (size_t)b * 256 + c;
    float vals[21];
    vals[0] = wr[256 + c] * p1[bc];
    float w2 = wr[512 + c], w4 = wr[768 + c];
#pragma unroll
    for (int j = 0; j < 4; ++j) vals[1 + j] = w2 * p2[bc * 4 + j];
#pragma unroll
    for (int r = 0; r < 16; ++r) vals[5 + r] = w4 * p4[bc * 16 + r];

    int lane = tid & 63, wid = tid >> 6;
    __shared__ float red[21][4];
    __shared__ float tot[21];
#pragma unroll
    for (int k = 0; k < 21; ++k) {
        float v = vals[k];
        v += __shfl_xor(v, 1);  v += __shfl_xor(v, 2);  v += __shfl_xor(v, 4);
        v += __shfl_xor(v, 8);  v += __shfl_xor(v, 16); v += __shfl_xor(v, 32);
        if (lane == 0) red[k][wid] = v;
    }
    __syncthreads();
    if (tid < 21) tot[tid] = red[tid][0] + red[tid][1] + red[tid][2] + red[tid][3];
    __syncthreads();
    if (tid < 16) {
        int r = tid;
        int rr = ((r >> 2) >> 1) * 2 + ((r & 3) >> 1);
        kadd[((size_t)(b * 128 + o)) * 16 + r] = bk[o] + tot[0] + tot[1 + rr] + tot[5 + r];
    }
}

// --------------------------- projection GEMMs ------------------------------
// MODE 0 (q): out[n,o] = x1t[n,:]·Wq[o,:] + bq[o]           (per b, M=1024,N=128)
// MODE 1 (k): out[n,o] = x2t[n,:]·Wk[o,:256] + kadd[b,o,reg(n)]
// MODE 2 (v): out[o,n] = Wv[o,:]·x2t[n,:] + bv[o]           (per b, M=256,N=1024)
// Both operands are read as [row][k] with k contiguous (16B/lane).
template <int MODE>
__global__ __launch_bounds__(256) void gemm_kernel(const unsigned short* __restrict__ A0,
                                                   const unsigned short* __restrict__ B0,
                                                   unsigned short* __restrict__ out0,
                                                   const float* __restrict__ bias,
                                                   const float* __restrict__ kadd) {
    int b = blockIdx.z;
    const unsigned short* A;
    const unsigned short* Bp;
    unsigned short* out;
    int lda, ldb, ldo;
    if (MODE == 0) { A = A0 + (size_t)b * 262144; lda = 256; Bp = B0; ldb = 256;  out = out0 + (size_t)b * 131072; ldo = 128; }
    if (MODE == 1) { A = A0 + (size_t)b * 262144; lda = 256; Bp = B0; ldb = 1024; out = out0 + (size_t)b * 131072; ldo = 128; }
    if (MODE == 2) { A = A0;                      lda = 256; Bp = B0 + (size_t)b * 262144; ldb = 256; out = out0 + (size_t)b * 262144; ldo = 1024; }

    int tid = threadIdx.x;
    int w = tid >> 6, lane = tid & 63;
    int lrow = lane & 15, lk8 = (lane >> 4) * 8;
    int row0 = blockIdx.x * 128 + (w >> 1) * 64;
    int col0 = blockIdx.y * 128 + (w & 1) * 64;

    f32x4 z = {0.f, 0.f, 0.f, 0.f};
    f32x4 acc[4][4];
#pragma unroll
    for (int i = 0; i < 4; ++i)
#pragma unroll
        for (int j = 0; j < 4; ++j) acc[i][j] = z;

    for (int kc = 0; kc < 256; kc += 32) {
        short8 af[4], bfr[4];
#pragma unroll
        for (int i = 0; i < 4; ++i)
            af[i] = ld8(A + (size_t)(row0 + i * 16 + lrow) * lda + kc + lk8);
#pragma unroll
        for (int j = 0; j < 4; ++j)
            bfr[j] = ld8(Bp + (size_t)(col0 + j * 16 + lrow) * ldb + kc + lk8);
#pragma unroll
        for (int i = 0; i < 4; ++i)
#pragma unroll
            for (int j = 0; j < 4; ++j) acc[i][j] = MFMA(af[i], bfr[j], acc[i][j]);
    }

#pragma unroll
    for (int i = 0; i < 4; ++i) {
#pragma unroll
        for (int j = 0; j < 4; ++j) {
            int col = col0 + j * 16 + lrow;
#pragma unroll
            for (int r = 0; r < 4; ++r) {
                int row = row0 + i * 16 + (lane >> 4) * 4 + r;
                float val = acc[i][j][r];
                if (MODE == 0) val += bias[col];
                if (MODE == 1) {
                    int h = row >> 5, ww = row & 31;
                    val += kadd[((size_t)(b * 128 + col)) * 16 + ((h >> 3) * 4 + (ww >> 3))];
                }
                if (MODE == 2) val += bias[row];
                out[(size_t)row * ldo + col] = f2bf(val);
            }
        }
    }
}

// --------------------------- flash attention -------------------------------
// block: (b, i-tile of 64); 4 waves x 16 query rows. j-tile = 64.
// Q/K read from [b][n][128] bf16 (16B frags), V from [b][256][1024] bf16.
__global__ __launch_bounds__(256) void attn_kernel(const unsigned short* __restrict__ qt,
                                                   const unsigned short* __restrict__ kt,
                                                   const unsigned short* __restrict__ vv,
                                                   const float* __restrict__ x1,
                                                   float* __restrict__ out) {
    int b = blockIdx.x >> 4;
    int i0 = (blockIdx.x & 15) * 64;
    int tid = threadIdx.x;
    int w = tid >> 6, lane = tid & 63;
    int lrow = lane & 15, lk8 = (lane >> 4) * 8;
    int iw = i0 + w * 16;

    __shared__ unsigned short plds[4][16][72];   // P strip per wave (pad 8)
    __shared__ float olds[4][16][260];           // O transpose (stride%32==4 -> 2-way)

    const unsigned short* qb = qt + ((size_t)b * 1024 + iw) * 128;
    const unsigned short* kb = kt + (size_t)b * 131072;
    const unsigned short* vb = vv + (size_t)b * 262144;

    short8 qf[4];
#pragma unroll
    for (int cc = 0; cc < 4; ++cc) qf[cc] = ld8(qb + (size_t)lrow * 128 + cc * 32 + lk8);

    f32x4 z = {0.f, 0.f, 0.f, 0.f};
    f32x4 oacc[16];
#pragma unroll
    for (int cb = 0; cb < 16; ++cb) oacc[cb] = z;
    float m_[4] = {-1e30f, -1e30f, -1e30f, -1e30f};
    float l_[4] = {0.f, 0.f, 0.f, 0.f};

    for (int j0 = 0; j0 < 1024; j0 += 64) {
        // ---- S strip: 16 rows x 64 cols ----
        f32x4 s[4];
#pragma unroll
        for (int jb = 0; jb < 4; ++jb) s[jb] = z;
#pragma unroll
        for (int jb = 0; jb < 4; ++jb)
#pragma unroll
            for (int cc = 0; cc < 4; ++cc) {
                short8 kf = ld8(kb + (size_t)(j0 + jb * 16 + lrow) * 128 + cc * 32 + lk8);
                s[jb] = MFMA(qf[cc], kf, s[jb]);
            }

        // ---- online softmax (rows live in 16-lane groups) ----
        float sc[4], rs[4];
#pragma unroll
        for (int r = 0; r < 4; ++r) {
            float t = fmaxf(fmaxf(s[0][r], s[1][r]), fmaxf(s[2][r], s[3][r]));
            t = fmaxf(t, __shfl_xor(t, 1));
            t = fmaxf(t, __shfl_xor(t, 2));
            t = fmaxf(t, __shfl_xor(t, 4));
            t = fmaxf(t, __shfl_xor(t, 8));
            float nm = fmaxf(m_[r], t);
            sc[r] = __expf(m_[r] - nm);
            m_[r] = nm;
            rs[r] = 0.f;
        }
#pragma unroll
        for (int jb = 0; jb < 4; ++jb)
#pragma unroll
            for (int r = 0; r < 4; ++r) {
                float p = __expf(s[jb][r] - m_[r]);
                rs[r] += p;
                plds[w][(lane >> 4) * 4 + r][jb * 16 + lrow] = f2bf(p);
            }
#pragma unroll
        for (int r = 0; r < 4; ++r) {
            float t = rs[r];
            t += __shfl_xor(t, 1);
            t += __shfl_xor(t, 2);
            t += __shfl_xor(t, 4);
            t += __shfl_xor(t, 8);
            l_[r] = l_[r] * sc[r] + t;
        }
#pragma unroll
        for (int cb = 0; cb < 16; ++cb)
#pragma unroll
            for (int r = 0; r < 4; ++r) oacc[cb][r] *= sc[r];

        __syncthreads();                               // P visible wave-wide
        short8 pa0 = ld8(&plds[w][lrow][lk8]);
        short8 pa1 = ld8(&plds[w][lrow][32 + lk8]);
        __syncthreads();                               // reads done before next write

        // ---- PV: O[i,c] += P[i,j] * V[c,j] ----
#pragma unroll
        for (int cb = 0; cb < 16; ++cb) {
            short8 vf0 = ld8(vb + (size_t)(cb * 16 + lrow) * 1024 + j0 + lk8);
            oacc[cb] = MFMA(pa0, vf0, oacc[cb]);
            short8 vf1 = ld8(vb + (size_t)(cb * 16 + lrow) * 1024 + j0 + 32 + lk8);
            oacc[cb] = MFMA(pa1, vf1, oacc[cb]);
        }
    }

    float inv[4];
#pragma unroll
    for (int r = 0; r < 4; ++r) inv[r] = 1.f / l_[r];
#pragma unroll
    for (int cb = 0; cb < 16; ++cb)
#pragma unroll
        for (int r = 0; r < 4; ++r)
            olds[w][(lane >> 4) * 4 + r][cb * 16 + lrow] = oacc[cb][r] * inv[r];
    __syncthreads();

    // coalesced store: 16 consecutive i per c (64B lines), + residual x1
    int il = lrow;
#pragma unroll 8
    for (int cc = 0; cc < 64; ++cc) {
        int c = cc * 4 + (lane >> 4);
        size_t g = ((size_t)b * 256 + c) * 1024 + iw + il;
        out[g] = olds[w][il][c] + x1[g];
    }
}

// ---------------------------------------------------------------------------
extern "C" void kernel_launch(void* const* d_in, const int* in_sizes, int n_in,
                              void* d_out, int out_size, void* d_ws, size_t ws_size,
                              hipStream_t stream) {
    const float* x1 = (const float*)d_in[0];
    const float* x2 = (const float*)d_in[1];
    const float* Wq = (const float*)d_in[2];
    const float* bq = (const float*)d_in[3];
    const float* Wk = (const float*)d_in[4];
    const float* bk = (const float*)d_in[5];
    const float* Wv = (const float*)d_in[6];
    const float* bv = (const float*)d_in[7];
    float* out = (float*)d_out;

    char* ws = (char*)d_ws;
    // workspace layout (bytes)
    unsigned short* x1t = (unsigned short*)(ws + 0);            // 16 MiB
    unsigned short* x2t = (unsigned short*)(ws + 16777216);     // 16 MiB
    unsigned short* qt  = (unsigned short*)(ws + 33554432);     // 8 MiB
    unsigned short* kt  = (unsigned short*)(ws + 41943040);     // 8 MiB
    unsigned short* v   = (unsigned short*)(ws + 50331648);     // 16 MiB
    float* p1   = (float*)(ws + 67108864);                      // 32 KiB
    float* p2   = (float*)(ws + 67141632);                      // 128 KiB
    float* p4   = (float*)(ws + 67272704);                      // 512 KiB
    float* kadd = (float*)(ws + 67796992);                      // 256 KiB
    unsigned short* wqb = (unsigned short*)(ws + 68059136);     // 64 KiB
    unsigned short* wkb = (unsigned short*)(ws + 68124672);     // 256 KiB
    unsigned short* wvb = (unsigned short*)(ws + 68386816);     // 128 KiB

    // weights -> bf16
    f2bf_kernel<<<128, 256, 0, stream>>>(Wq, wqb, 32768);
    f2bf_kernel<<<512, 256, 0, stream>>>(Wk, wkb, 131072);
    f2bf_kernel<<<256, 256, 0, stream>>>(Wv, wvb, 65536);

    // x1,x2 -> transposed bf16 [b][n][c]
    transpose_kernel<<<dim3(16, 4, 32), 256, 0, stream>>>(x1, x1t);
    transpose_kernel<<<dim3(16, 4, 32), 256, 0, stream>>>(x2, x2t);

    // pyramid pools + k-bias fold
    pool_kernel<<<8192, 64, 0, stream>>>(x2, p1, p2, p4);
    kadd_kernel<<<4096, 256, 0, stream>>>(Wk, bk, p1, p2, p4, kadd);

    // projections
    gemm_kernel<0><<<dim3(8, 1, 32), 256, 0, stream>>>(x1t, wqb, qt, bq, nullptr);
    gemm_kernel<1><<<dim3(8, 1, 32), 256, 0, stream>>>(x2t, wkb, kt, nullptr, kadd);
    gemm_kernel<2><<<dim3(2, 8, 32), 256, 0, stream>>>(wvb, x2t, v, bv, nullptr);

    // flash attention + residual
    attn_kernel<<<512, 256, 0, stream>>>(qt, kt, v, x1, out);
}